// Round 10
// baseline (171.617 us; speedup 1.0000x reference)
//
#include <hip/hip_runtime.h>

#define NB 4
#define NC 128
#define NH 184
#define NW 320
#define TH 8                                      // K2: output h-rows per block
#define TWB 32                                    // K2: output w-cols per block
#define HWPIX (NH * NW)                           // 58880
#define NPIX (NB * NH * NW)                       // 235520 pixels per tensor
#define ZOFF ((size_t)2 * NPIX * NC)              // zero page offset (shorts)
#define IVOFF (ZOFF * 2 + 512)                    // invn byte offset in ws
#define WS_NEEDED (IVOFF + (size_t)2 * NPIX * 4)  // + 1.9 MB invn

typedef __attribute__((ext_vector_type(8))) short bf16x8;
typedef __attribute__((ext_vector_type(4))) float f32x4;

__device__ __forceinline__ unsigned short f2bf(float f) {
  unsigned int u = __float_as_uint(f);
  u = u + 0x7fffu + ((u >> 16) & 1u);             // RNE
  return (unsigned short)(u >> 16);
}

// ========== K1: raw fp32 CHW -> raw bf16 HWC8 [cb][pix][8] + invn norms ==========
// Deferred normalization => no 128-channel gather => no cross-wave transpose.
// Reads: 1KB contiguous. Stores: 4KB sequential per cb-stream (4x1KB instrs).
// Per-wave 4KB LDS bounce (no barrier); one block barrier for sumsq reduce.
__global__ __launch_bounds__(256) void conv_hwc8(const float* __restrict__ f1,
                                                 const float* __restrict__ f2,
                                                 unsigned short* __restrict__ fn,
                                                 float* __restrict__ invn) {
  const int t  = threadIdx.x;
  const int wv = t >> 6;
  const int l6 = t & 63;
  const int tensor = blockIdx.y;
  const float* src = tensor ? f2 : f1;
  unsigned short* dst = fn + (tensor ? (size_t)NPIX * NC : 0);
  float* invd = invn + (tensor ? (size_t)NPIX : 0);

  const int p0 = blockIdx.x * 256;        // flat pixel base; b uniform (58880=230*256)
  const int b  = blockIdx.x / 230;
  const int hw0 = p0 - b * HWPIX;
  const float* src_b = src + (size_t)b * NC * HWPIX + hw0;

  __shared__ __align__(16) unsigned short bounce[4][2048];  // 4KB per wave
  __shared__ f32x4 scr[4][64];

  f32x4 ssv = {0.f, 0.f, 0.f, 0.f};
  unsigned short* bw = &bounce[wv][0];

  #pragma unroll
  for (int chunk = 0; chunk < 4; ++chunk) {
    const int cb = chunk * 4 + wv;        // channel block [cb*8, cb*8+8)
    const float* sp = src_b + (size_t)(cb * 8) * HWPIX + l6 * 4;
    f32x4 v[8];
    #pragma unroll
    for (int i = 0; i < 8; ++i)           // 64 lanes x 16B = 1KB contiguous
      v[i] = *reinterpret_cast<const f32x4*>(sp + (size_t)i * HWPIX);
    // pack raw bf16 fragments into swizzled per-wave LDS
    #pragma unroll
    for (int s = 0; s < 4; ++s) {
      bf16x8 sv;
      #pragma unroll
      for (int i = 0; i < 8; ++i) {
        const float x = v[i][s];
        ssv[s] += x * x;                  // raw fp32 sumsq (reference formula)
        sv[i] = (short)f2bf(x);
      }
      const int px  = l6 * 4 + s;
      const int a16 = px ^ ((px >> 3) & 7);     // bank swizzle (both sides)
      *reinterpret_cast<bf16x8*>(bw + a16 * 8) = sv;
    }
    // redistribute: lane j takes pixel k*64+j -> 1KB-contiguous stores
    #pragma unroll
    for (int k = 0; k < 4; ++k) {
      const int p   = k * 64 + l6;
      const int a16 = p ^ ((p >> 3) & 7);
      bf16x8 frag = *reinterpret_cast<const bf16x8*>(bw + a16 * 8);
      *reinterpret_cast<bf16x8*>(dst + ((size_t)cb * NPIX + p0 + p) * 8) = frag;
    }
  }

  scr[wv][l6] = ssv;
  __syncthreads();
  if (t < 64) {
    f32x4 s = scr[0][t] + scr[1][t] + scr[2][t] + scr[3][t];
    f32x4 iv;
    #pragma unroll
    for (int px = 0; px < 4; ++px) iv[px] = 1.f / fmaxf(sqrtf(s[px]), 1e-12f);
    *reinterpret_cast<f32x4*>(invd + p0 + t * 4) = iv;
  }
  // zero page for K2's OOB loads (same-stream ordering)
  if (blockIdx.x == 0 && tensor == 0 && t < 128) fn[ZOFF + t] = 0;
}

// ========== K2: vertical-tiled banded MFMA on HWC8; norms in epilogue ==========
__global__ __launch_bounds__(128, 2) void corr_hwc2(const unsigned short* __restrict__ fn,
                                                    const float* __restrict__ invn,
                                                    float* __restrict__ out) {
  // grid 920 = 8*115; ht-major so same-XCD neighbors share f2 rows in L2
  const int bid = blockIdx.x;
  const int swz = (bid & 7) * 115 + (bid >> 3);
  const int ht  = swz % 23;
  const int wtb = (swz / 23) % 10;
  const int b   = swz / 230;
  const int h0  = ht * TH;
  const int w0  = wtb * TWB;

  const int t = threadIdx.x;                      // 0..127 (2 waves)
  const int lane = t & 63;
  const int wv = t >> 6;                          // wave owns w in [wv*16, wv*16+16)
  const int q = lane >> 4;
  const int n = lane & 15;

  const unsigned short* f1n = fn;
  const unsigned short* f2n = fn + (size_t)NPIX * NC;
  const unsigned short* zpage = fn + ZOFF;
  const float* inv1 = invn + (size_t)b * HWPIX;
  const float* inv2 = invn + NPIX + (size_t)b * HWPIX;

  __shared__ float out_s[2][9][17];               // per-wave transpose buffer

  // ---- A fragments: stream (kk*4+q), pixel (h0+hh, w0+wv*16+n) ----
  bf16x8 av[TH][4];
  #pragma unroll
  for (int hh = 0; hh < TH; ++hh) {
    const size_t pA = (size_t)b * HWPIX + (size_t)(h0 + hh) * NW + w0 + wv * 16 + n;
    #pragma unroll
    for (int kk = 0; kk < 4; ++kk)
      av[hh][kk] = *reinterpret_cast<const bf16x8*>(f1n + ((size_t)(kk * 4 + q) * NPIX + pA) * 8);
  }

  const int j0 = w0 + wv * 16 - 4 + n;            // N-tile 0 col (may be <0)
  const int j1 = j0 + 16;                         // N-tile 1 col (may be >=NW)

  bf16x8 bA[2][4], bB[2][4];

#define LD_ROW(BUF, RR) do {                                                     \
    const int hr_ = h0 + (RR);                                                   \
    const bool rok_ = (hr_ >= 0) && (hr_ < NH);                                  \
    const size_t rp_ = (size_t)b * HWPIX + (size_t)(rok_ ? hr_ : 0) * NW;        \
    _Pragma("unroll")                                                            \
    for (int kk = 0; kk < 4; ++kk) {                                             \
      const unsigned short* q0_ = (rok_ && j0 >= 0)                              \
          ? (f2n + ((size_t)(kk * 4 + q) * NPIX + rp_ + j0) * 8) : zpage;        \
      BUF[0][kk] = *reinterpret_cast<const bf16x8*>(q0_);                        \
    }                                                                            \
    _Pragma("unroll")                                                            \
    for (int kk = 0; kk < 4; ++kk) {                                             \
      const unsigned short* q1_ = (rok_ && j1 < NW)                              \
          ? (f2n + ((size_t)(kk * 4 + q) * NPIX + rp_ + j1) * 8) : zpage;        \
      BUF[1][kk] = *reinterpret_cast<const bf16x8*>(q1_);                        \
    }                                                                            \
  } while (0)

#define COMPUTE(BUF, RR) do {                                                    \
    _Pragma("unroll")                                                            \
    for (int hh = 0; hh < TH; ++hh) {                                            \
      const int dyi_ = hh - (RR) + 4;             /* dy+4; wave-uniform */       \
      if (dyi_ >= 0 && dyi_ <= 8) {                                              \
        f32x4 a0 = {0.f, 0.f, 0.f, 0.f};                                         \
        f32x4 a1 = {0.f, 0.f, 0.f, 0.f};                                         \
        _Pragma("unroll")                                                        \
        for (int kk = 0; kk < 4; ++kk) {                                         \
          a0 = __builtin_amdgcn_mfma_f32_16x16x32_bf16(av[hh][kk], BUF[0][kk], a0, 0, 0, 0); \
          a1 = __builtin_amdgcn_mfma_f32_16x16x32_bf16(av[hh][kk], BUF[1][kk], a1, 0, 0, 0); \
        }                                                                        \
        _Pragma("unroll")                                                        \
        for (int r = 0; r < 4; ++r) {            /* dx+4 = 4q+r+8-n (T=0) */     \
          const int dxi0 = 4 * q + r + 8 - n;                                    \
          if (dxi0 >= 0 && dxi0 <= 8) out_s[wv][dxi0][4 * q + r] = a0[r];        \
          const int dxi1 = 4 * q + r - 8 - n;    /* T=1 */                       \
          if (dxi1 >= 0 && dxi1 <= 8) out_s[wv][dxi1][4 * q + r] = a1[r];        \
        }                                                                        \
        _Pragma("unroll")                                                        \
        for (int i = 0; i < 3; ++i) {                                            \
          const int idx = i * 64 + lane;                                         \
          if (idx < 144) {                                                       \
            const int dx_ = idx >> 4;                                            \
            const int wc_ = idx & 15;                                            \
            const int wgl = w0 + wv * 16 + wc_;                                  \
            const int hg  = h0 + hh;                                             \
            int jj = wgl - dx_ + 4;  jj = jj < 0 ? 0 : (jj >= NW ? NW - 1 : jj); \
            int hr2 = hg - dyi_ + 4; hr2 = hr2 < 0 ? 0 : (hr2 >= NH ? NH - 1 : hr2); \
            const float o = out_s[wv][dx_][wc_]                                  \
                * inv1[(size_t)hg * NW + wgl] * inv2[(size_t)hr2 * NW + jj];     \
            out[((size_t)(b * 81 + dyi_ * 9 + dx_) * NH + hg) * NW + wgl] = o;   \
          }                                                                      \
        }                                                                        \
      }                                                                          \
    }                                                                            \
  } while (0)

  // ---- main loop over 16 f2 rows (rr = hr - h0 in [-4, 11]), double-buffered ----
  LD_ROW(bA, -4);
  for (int k = 0; k < 7; ++k) {
    const int rr = 2 * k - 4;
    LD_ROW(bB, rr + 1);
    __builtin_amdgcn_sched_barrier(0);
    COMPUTE(bA, rr);
    LD_ROW(bA, rr + 2);
    __builtin_amdgcn_sched_barrier(0);
    COMPUTE(bB, rr + 1);
  }
  LD_ROW(bB, 11);
  __builtin_amdgcn_sched_barrier(0);
  COMPUTE(bA, 10);
  COMPUTE(bB, 11);

#undef LD_ROW
#undef COMPUTE
}

// ========== fallback: round-2 fused kernel (used if ws too small) ==========
__global__ __launch_bounds__(256) void corr_mfma(const float* __restrict__ f1,
                                                 const float* __restrict__ f2,
                                                 float* __restrict__ out) {
  const int wt = blockIdx.x;
  const int h  = blockIdx.y;
  const int b  = blockIdx.z;
  const int w0 = wt * 64;
  const int t  = threadIdx.x;
  const int lane = t & 63;
  const int wave = t >> 6;

  __shared__ __align__(16) unsigned short a_s[64 * NC];
  __shared__ __align__(16) unsigned short b_s[80 * NC];
  __shared__ float scr[80][17];
  __shared__ float invn1_s[64];
  __shared__ float invn2_s[80];
  __shared__ float out_s[9][64];

  const size_t HW = (size_t)NH * NW;

  {
    const int w  = t & 63;
    const int cg = t >> 6;
    float ss = 0.f;
    #pragma unroll
    for (int cc = 0; cc < 4; ++cc) {
      const int cb = cg * 32 + cc * 8;
      const float* p = f1 + ((size_t)b * NC + cb) * HW + (size_t)h * NW + w0 + w;
      float v[8];
      #pragma unroll
      for (int i = 0; i < 8; ++i) v[i] = p[i * HW];
      bf16x8 sv;
      #pragma unroll
      for (int i = 0; i < 8; ++i) {
        unsigned int u = __float_as_uint(v[i]);
        u = (u + 0x7fffu + ((u >> 16) & 1u)) & 0xffff0000u;
        float vb = __uint_as_float(u);
        ss += vb * vb;
        sv[i] = (short)(u >> 16);
      }
      const int idx = (w * NC + cb) ^ ((w & 7) << 3);
      *reinterpret_cast<bf16x8*>(&a_s[idx]) = sv;
    }
    scr[w][cg] = ss;
  }
  __syncthreads();
  if (t < 64) {
    float s = scr[t][0] + scr[t][1] + scr[t][2] + scr[t][3];
    invn1_s[t] = 1.f / fmaxf(sqrtf(s), 1e-12f);
  }

  for (int dyi = 0; dyi < 9; ++dyi) {
    __syncthreads();
    const int hr = h + 4 - dyi;
    {
      const int jl16 = t & 15;
      const int cg   = t >> 4;
      const int cb   = cg * 8;
      const bool rowok = (hr >= 0) && (hr < NH);
      #pragma unroll
      for (int s5 = 0; s5 < 5; ++s5) {
        const int jl = s5 * 16 + jl16;
        const int jg = w0 - 4 + jl;
        float v[8];
        if (rowok && jg >= 0 && jg < NW) {
          const float* p = f2 + ((size_t)b * NC + cb) * HW + (size_t)hr * NW + jg;
          #pragma unroll
          for (int i = 0; i < 8; ++i) v[i] = p[i * HW];
        } else {
          #pragma unroll
          for (int i = 0; i < 8; ++i) v[i] = 0.f;
        }
        float ss = 0.f;
        bf16x8 sv;
        #pragma unroll
        for (int i = 0; i < 8; ++i) {
          unsigned int u = __float_as_uint(v[i]);
          u = (u + 0x7fffu + ((u >> 16) & 1u)) & 0xffff0000u;
          float vb = __uint_as_float(u);
          ss += vb * vb;
          sv[i] = (short)(u >> 16);
        }
        const int idx = (jl * NC + cb) ^ ((jl & 7) << 3);
        *reinterpret_cast<bf16x8*>(&b_s[idx]) = sv;
        scr[jl][cg] = ss;
      }
    }
    __syncthreads();
    if (t < 80) {
      float s = 0.f;
      #pragma unroll
      for (int i = 0; i < 16; ++i) s += scr[t][i];
      invn2_s[t] = 1.f / fmaxf(sqrtf(s), 1e-12f);
    }
    __syncthreads();
    {
      const int m = wave;
      const int q = lane >> 4;
      const int n = lane & 15;
      f32x4 acc0 = {0.f, 0.f, 0.f, 0.f};
      f32x4 acc1 = {0.f, 0.f, 0.f, 0.f};
      const int wl  = m * 16 + n;
      const int jl0 = m * 16 + n;
      const int jl1 = m * 16 + 16 + n;
      #pragma unroll
      for (int kk = 0; kk < 4; ++kk) {
        const int c0 = kk * 32 + q * 8;
        bf16x8 avv = *reinterpret_cast<const bf16x8*>(&a_s[(wl  * NC + c0) ^ ((wl  & 7) << 3)]);
        bf16x8 bv0 = *reinterpret_cast<const bf16x8*>(&b_s[(jl0 * NC + c0) ^ ((jl0 & 7) << 3)]);
        bf16x8 bv1 = *reinterpret_cast<const bf16x8*>(&b_s[(jl1 * NC + c0) ^ ((jl1 & 7) << 3)]);
        acc0 = __builtin_amdgcn_mfma_f32_16x16x32_bf16(avv, bv0, acc0, 0, 0, 0);
        acc1 = __builtin_amdgcn_mfma_f32_16x16x32_bf16(avv, bv1, acc1, 0, 0, 0);
      }
      #pragma unroll
      for (int T = 0; T < 2; ++T) {
        const f32x4 a = T ? acc1 : acc0;
        const int jl = m * 16 + T * 16 + n;
        const float i2 = invn2_s[jl];
        #pragma unroll
        for (int r = 0; r < 4; ++r) {
          const int wr = m * 16 + q * 4 + r;
          const int dx = wr + 4 - jl;
          if (dx >= -4 && dx <= 4) {
            out_s[dx + 4][wr] = a[r] * invn1_s[wr] * i2;
          }
        }
      }
    }
    __syncthreads();
    #pragma unroll
    for (int kidx = 0; kidx < 3; ++kidx) {
      const int k = kidx * 256 + t;
      if (k < 9 * 64) {
        const int dx = k >> 6;
        const int wl = k & 63;
        const int d  = dyi * 9 + dx;
        out[(((size_t)b * 81 + d) * NH + h) * NW + w0 + wl] = out_s[dx][wl];
      }
    }
  }
}

extern "C" void kernel_launch(void* const* d_in, const int* in_sizes, int n_in,
                              void* d_out, int out_size, void* d_ws, size_t ws_size,
                              hipStream_t stream) {
  const float* f1 = (const float*)d_in[0];
  const float* f2 = (const float*)d_in[1];
  float* out = (float*)d_out;
  if (d_ws != nullptr && ws_size >= WS_NEEDED) {
    unsigned short* fn = (unsigned short*)d_ws;
    float* invn = (float*)((char*)d_ws + IVOFF);
    conv_hwc8<<<dim3(920, 2), 256, 0, stream>>>(f1, f2, fn, invn);
    corr_hwc2<<<dim3(920), 128, 0, stream>>>(fn, invn, out);
  } else {
    corr_mfma<<<dim3(5, NH, NB), 256, 0, stream>>>(f1, f2, out);
  }
}

// Round 11
// 134.197 us; speedup vs baseline: 1.2788x; 1.2788x over previous
//
#include <hip/hip_runtime.h>

#define NB 4
#define NC 128
#define NH 184
#define NW 320
#define TH 8                                      // K2: output h-rows per block
#define TWB 32                                    // K2: output w-cols per block
#define HWPIX (NH * NW)                           // 58880
#define NPIX (NB * NH * NW)                       // 235520 pixels per tensor
#define ZOFF ((size_t)2 * NPIX * NC)              // zero page offset (shorts)
#define IVOFF (ZOFF * 2 + 512)                    // invn byte offset in ws
#define WS_NEEDED (IVOFF + (size_t)2 * NPIX * 4)  // + 1.9 MB invn

typedef __attribute__((ext_vector_type(8))) short bf16x8;
typedef __attribute__((ext_vector_type(4))) float f32x4;

__device__ __forceinline__ unsigned short f2bf(float f) {
  unsigned int u = __float_as_uint(f);
  u = u + 0x7fffu + ((u >> 16) & 1u);             // RNE
  return (unsigned short)(u >> 16);
}

// ========== K1: raw fp32 CHW -> raw bf16 HWC8 [cb][pix][8] + invn norms ==========
// (UNCHANGED from R10 — measured ~56us, at HBM roofline for 362MB)
__global__ __launch_bounds__(256) void conv_hwc8(const float* __restrict__ f1,
                                                 const float* __restrict__ f2,
                                                 unsigned short* __restrict__ fn,
                                                 float* __restrict__ invn) {
  const int t  = threadIdx.x;
  const int wv = t >> 6;
  const int l6 = t & 63;
  const int tensor = blockIdx.y;
  const float* src = tensor ? f2 : f1;
  unsigned short* dst = fn + (tensor ? (size_t)NPIX * NC : 0);
  float* invd = invn + (tensor ? (size_t)NPIX : 0);

  const int p0 = blockIdx.x * 256;        // flat pixel base; b uniform (58880=230*256)
  const int b  = blockIdx.x / 230;
  const int hw0 = p0 - b * HWPIX;
  const float* src_b = src + (size_t)b * NC * HWPIX + hw0;

  __shared__ __align__(16) unsigned short bounce[4][2048];  // 4KB per wave
  __shared__ f32x4 scr[4][64];

  f32x4 ssv = {0.f, 0.f, 0.f, 0.f};
  unsigned short* bw = &bounce[wv][0];

  #pragma unroll
  for (int chunk = 0; chunk < 4; ++chunk) {
    const int cb = chunk * 4 + wv;        // channel block [cb*8, cb*8+8)
    const float* sp = src_b + (size_t)(cb * 8) * HWPIX + l6 * 4;
    f32x4 v[8];
    #pragma unroll
    for (int i = 0; i < 8; ++i)           // 64 lanes x 16B = 1KB contiguous
      v[i] = *reinterpret_cast<const f32x4*>(sp + (size_t)i * HWPIX);
    // pack raw bf16 fragments into swizzled per-wave LDS
    #pragma unroll
    for (int s = 0; s < 4; ++s) {
      bf16x8 sv;
      #pragma unroll
      for (int i = 0; i < 8; ++i) {
        const float x = v[i][s];
        ssv[s] += x * x;                  // raw fp32 sumsq (reference formula)
        sv[i] = (short)f2bf(x);
      }
      const int px  = l6 * 4 + s;
      const int a16 = px ^ ((px >> 3) & 7);     // bank swizzle (both sides)
      *reinterpret_cast<bf16x8*>(bw + a16 * 8) = sv;
    }
    // redistribute: lane j takes pixel k*64+j -> 1KB-contiguous stores
    #pragma unroll
    for (int k = 0; k < 4; ++k) {
      const int p   = k * 64 + l6;
      const int a16 = p ^ ((p >> 3) & 7);
      bf16x8 frag = *reinterpret_cast<const bf16x8*>(bw + a16 * 8);
      *reinterpret_cast<bf16x8*>(dst + ((size_t)cb * NPIX + p0 + p) * 8) = frag;
    }
  }

  scr[wv][l6] = ssv;
  __syncthreads();
  if (t < 64) {
    f32x4 s = scr[0][t] + scr[1][t] + scr[2][t] + scr[3][t];
    f32x4 iv;
    #pragma unroll
    for (int px = 0; px < 4; ++px) iv[px] = 1.f / fmaxf(sqrtf(s[px]), 1e-12f);
    *reinterpret_cast<f32x4*>(invd + p0 + t * 4) = iv;
  }
  // zero page for K2's OOB loads (same-stream ordering)
  if (blockIdx.x == 0 && tensor == 0 && t < 128) fn[ZOFF + t] = 0;
}

// ========== K2: vertical-tiled banded MFMA on HWC8; norms via LDS preload ==========
__global__ __launch_bounds__(128, 2) void corr_hwc2(const unsigned short* __restrict__ fn,
                                                    const float* __restrict__ invn,
                                                    float* __restrict__ out) {
  // grid 920 = 8*115; ht-major so same-XCD neighbors share f2 rows in L2
  const int bid = blockIdx.x;
  const int swz = (bid & 7) * 115 + (bid >> 3);
  const int ht  = swz % 23;
  const int wtb = (swz / 23) % 10;
  const int b   = swz / 230;
  const int h0  = ht * TH;
  const int w0  = wtb * TWB;

  const int t = threadIdx.x;                      // 0..127 (2 waves)
  const int lane = t & 63;
  const int wv = t >> 6;                          // wave owns w in [wv*16, wv*16+16)
  const int q = lane >> 4;
  const int n = lane & 15;

  const unsigned short* f1n = fn;
  const unsigned short* f2n = fn + (size_t)NPIX * NC;
  const unsigned short* zpage = fn + ZOFF;
  const float* inv1 = invn + (size_t)b * HWPIX;
  const float* inv2 = invn + NPIX + (size_t)b * HWPIX;

  __shared__ float out_s[2][9][17];               // per-wave transpose buffer
  __shared__ float inv1_s[TH][32];                // rows h0..h0+7, cols w0..w0+31
  __shared__ float inv2_s[16][40];                // rows h0-4..h0+11, cols w0-4..w0+35 (clamped)

  // ---- one-time norm preload (R10's per-output global loads were the 4x regression) ----
  for (int i = t; i < TH * 32; i += 128) {
    const int hh = i >> 5, wc = i & 31;
    inv1_s[hh][wc] = inv1[(size_t)(h0 + hh) * NW + w0 + wc];
  }
  for (int i = t; i < 16 * 40; i += 128) {
    const int rr = i / 40, cc = i - rr * 40;
    int hr = h0 + rr - 4; hr = hr < 0 ? 0 : (hr >= NH ? NH - 1 : hr);
    int jj = w0 + cc - 4; jj = jj < 0 ? 0 : (jj >= NW ? NW - 1 : jj);
    inv2_s[rr][cc] = inv2[(size_t)hr * NW + jj];
  }
  __syncthreads();

  // ---- A fragments: stream (kk*4+q), pixel (h0+hh, w0+wv*16+n) ----
  bf16x8 av[TH][4];
  #pragma unroll
  for (int hh = 0; hh < TH; ++hh) {
    const size_t pA = (size_t)b * HWPIX + (size_t)(h0 + hh) * NW + w0 + wv * 16 + n;
    #pragma unroll
    for (int kk = 0; kk < 4; ++kk)
      av[hh][kk] = *reinterpret_cast<const bf16x8*>(f1n + ((size_t)(kk * 4 + q) * NPIX + pA) * 8);
  }

  const int j0 = w0 + wv * 16 - 4 + n;            // N-tile 0 col (may be <0)
  const int j1 = j0 + 16;                         // N-tile 1 col (may be >=NW)

  bf16x8 bA[2][4], bB[2][4];

#define LD_ROW(BUF, RR) do {                                                     \
    const int hr_ = h0 + (RR);                                                   \
    const bool rok_ = (hr_ >= 0) && (hr_ < NH);                                  \
    const size_t rp_ = (size_t)b * HWPIX + (size_t)(rok_ ? hr_ : 0) * NW;        \
    _Pragma("unroll")                                                            \
    for (int kk = 0; kk < 4; ++kk) {                                             \
      const unsigned short* q0_ = (rok_ && j0 >= 0)                              \
          ? (f2n + ((size_t)(kk * 4 + q) * NPIX + rp_ + j0) * 8) : zpage;        \
      BUF[0][kk] = *reinterpret_cast<const bf16x8*>(q0_);                        \
    }                                                                            \
    _Pragma("unroll")                                                            \
    for (int kk = 0; kk < 4; ++kk) {                                             \
      const unsigned short* q1_ = (rok_ && j1 < NW)                              \
          ? (f2n + ((size_t)(kk * 4 + q) * NPIX + rp_ + j1) * 8) : zpage;        \
      BUF[1][kk] = *reinterpret_cast<const bf16x8*>(q1_);                        \
    }                                                                            \
  } while (0)

#define COMPUTE(BUF, RR) do {                                                    \
    _Pragma("unroll")                                                            \
    for (int hh = 0; hh < TH; ++hh) {                                            \
      const int dyi_ = hh - (RR) + 4;             /* dy+4; wave-uniform */       \
      if (dyi_ >= 0 && dyi_ <= 8) {                                              \
        f32x4 a0 = {0.f, 0.f, 0.f, 0.f};                                         \
        f32x4 a1 = {0.f, 0.f, 0.f, 0.f};                                         \
        _Pragma("unroll")                                                        \
        for (int kk = 0; kk < 4; ++kk) {                                         \
          a0 = __builtin_amdgcn_mfma_f32_16x16x32_bf16(av[hh][kk], BUF[0][kk], a0, 0, 0, 0); \
          a1 = __builtin_amdgcn_mfma_f32_16x16x32_bf16(av[hh][kk], BUF[1][kk], a1, 0, 0, 0); \
        }                                                                        \
        _Pragma("unroll")                                                        \
        for (int r = 0; r < 4; ++r) {            /* dx+4 = 4q+r+8-n (T=0) */     \
          const int dxi0 = 4 * q + r + 8 - n;                                    \
          if (dxi0 >= 0 && dxi0 <= 8) out_s[wv][dxi0][4 * q + r] = a0[r];        \
          const int dxi1 = 4 * q + r - 8 - n;    /* T=1 */                       \
          if (dxi1 >= 0 && dxi1 <= 8) out_s[wv][dxi1][4 * q + r] = a1[r];        \
        }                                                                        \
        _Pragma("unroll")                                                        \
        for (int i = 0; i < 3; ++i) {                                            \
          const int idx = i * 64 + lane;                                         \
          if (idx < 144) {                                                       \
            const int dx_ = idx >> 4;                                            \
            const int wc_ = idx & 15;                                            \
            const float o = out_s[wv][dx_][wc_]                                  \
                * inv1_s[hh][wv * 16 + wc_]                                      \
                * inv2_s[(RR) + 4][wv * 16 + wc_ - dx_ + 8];                     \
            out[((size_t)(b * 81 + dyi_ * 9 + dx_) * NH + (h0 + hh)) * NW        \
                + w0 + wv * 16 + wc_] = o;                                       \
          }                                                                      \
        }                                                                        \
      }                                                                          \
    }                                                                            \
  } while (0)

  // ---- main loop over 16 f2 rows (rr = hr - h0 in [-4, 11]), double-buffered ----
  LD_ROW(bA, -4);
  for (int k = 0; k < 7; ++k) {
    const int rr = 2 * k - 4;
    LD_ROW(bB, rr + 1);
    __builtin_amdgcn_sched_barrier(0);
    COMPUTE(bA, rr);
    LD_ROW(bA, rr + 2);
    __builtin_amdgcn_sched_barrier(0);
    COMPUTE(bB, rr + 1);
  }
  LD_ROW(bB, 11);
  __builtin_amdgcn_sched_barrier(0);
  COMPUTE(bA, 10);
  COMPUTE(bB, 11);

#undef LD_ROW
#undef COMPUTE
}

// ========== fallback: round-2 fused kernel (used if ws too small) ==========
__global__ __launch_bounds__(256) void corr_mfma(const float* __restrict__ f1,
                                                 const float* __restrict__ f2,
                                                 float* __restrict__ out) {
  const int wt = blockIdx.x;
  const int h  = blockIdx.y;
  const int b  = blockIdx.z;
  const int w0 = wt * 64;
  const int t  = threadIdx.x;
  const int lane = t & 63;
  const int wave = t >> 6;

  __shared__ __align__(16) unsigned short a_s[64 * NC];
  __shared__ __align__(16) unsigned short b_s[80 * NC];
  __shared__ float scr[80][17];
  __shared__ float invn1_s[64];
  __shared__ float invn2_s[80];
  __shared__ float out_s[9][64];

  const size_t HW = (size_t)NH * NW;

  {
    const int w  = t & 63;
    const int cg = t >> 6;
    float ss = 0.f;
    #pragma unroll
    for (int cc = 0; cc < 4; ++cc) {
      const int cb = cg * 32 + cc * 8;
      const float* p = f1 + ((size_t)b * NC + cb) * HW + (size_t)h * NW + w0 + w;
      float v[8];
      #pragma unroll
      for (int i = 0; i < 8; ++i) v[i] = p[i * HW];
      bf16x8 sv;
      #pragma unroll
      for (int i = 0; i < 8; ++i) {
        unsigned int u = __float_as_uint(v[i]);
        u = (u + 0x7fffu + ((u >> 16) & 1u)) & 0xffff0000u;
        float vb = __uint_as_float(u);
        ss += vb * vb;
        sv[i] = (short)(u >> 16);
      }
      const int idx = (w * NC + cb) ^ ((w & 7) << 3);
      *reinterpret_cast<bf16x8*>(&a_s[idx]) = sv;
    }
    scr[w][cg] = ss;
  }
  __syncthreads();
  if (t < 64) {
    float s = scr[t][0] + scr[t][1] + scr[t][2] + scr[t][3];
    invn1_s[t] = 1.f / fmaxf(sqrtf(s), 1e-12f);
  }

  for (int dyi = 0; dyi < 9; ++dyi) {
    __syncthreads();
    const int hr = h + 4 - dyi;
    {
      const int jl16 = t & 15;
      const int cg   = t >> 4;
      const int cb   = cg * 8;
      const bool rowok = (hr >= 0) && (hr < NH);
      #pragma unroll
      for (int s5 = 0; s5 < 5; ++s5) {
        const int jl = s5 * 16 + jl16;
        const int jg = w0 - 4 + jl;
        float v[8];
        if (rowok && jg >= 0 && jg < NW) {
          const float* p = f2 + ((size_t)b * NC + cb) * HW + (size_t)hr * NW + jg;
          #pragma unroll
          for (int i = 0; i < 8; ++i) v[i] = p[i * HW];
        } else {
          #pragma unroll
          for (int i = 0; i < 8; ++i) v[i] = 0.f;
        }
        float ss = 0.f;
        bf16x8 sv;
        #pragma unroll
        for (int i = 0; i < 8; ++i) {
          unsigned int u = __float_as_uint(v[i]);
          u = (u + 0x7fffu + ((u >> 16) & 1u)) & 0xffff0000u;
          float vb = __uint_as_float(u);
          ss += vb * vb;
          sv[i] = (short)(u >> 16);
        }
        const int idx = (jl * NC + cb) ^ ((jl & 7) << 3);
        *reinterpret_cast<bf16x8*>(&b_s[idx]) = sv;
        scr[jl][cg] = ss;
      }
    }
    __syncthreads();
    if (t < 80) {
      float s = 0.f;
      #pragma unroll
      for (int i = 0; i < 16; ++i) s += scr[t][i];
      invn2_s[t] = 1.f / fmaxf(sqrtf(s), 1e-12f);
    }
    __syncthreads();
    {
      const int m = wave;
      const int q = lane >> 4;
      const int n = lane & 15;
      f32x4 acc0 = {0.f, 0.f, 0.f, 0.f};
      f32x4 acc1 = {0.f, 0.f, 0.f, 0.f};
      const int wl  = m * 16 + n;
      const int jl0 = m * 16 + n;
      const int jl1 = m * 16 + 16 + n;
      #pragma unroll
      for (int kk = 0; kk < 4; ++kk) {
        const int c0 = kk * 32 + q * 8;
        bf16x8 avv = *reinterpret_cast<const bf16x8*>(&a_s[(wl  * NC + c0) ^ ((wl  & 7) << 3)]);
        bf16x8 bv0 = *reinterpret_cast<const bf16x8*>(&b_s[(jl0 * NC + c0) ^ ((jl0 & 7) << 3)]);
        bf16x8 bv1 = *reinterpret_cast<const bf16x8*>(&b_s[(jl1 * NC + c0) ^ ((jl1 & 7) << 3)]);
        acc0 = __builtin_amdgcn_mfma_f32_16x16x32_bf16(avv, bv0, acc0, 0, 0, 0);
        acc1 = __builtin_amdgcn_mfma_f32_16x16x32_bf16(avv, bv1, acc1, 0, 0, 0);
      }
      #pragma unroll
      for (int T = 0; T < 2; ++T) {
        const f32x4 a = T ? acc1 : acc0;
        const int jl = m * 16 + T * 16 + n;
        const float i2 = invn2_s[jl];
        #pragma unroll
        for (int r = 0; r < 4; ++r) {
          const int wr = m * 16 + q * 4 + r;
          const int dx = wr + 4 - jl;
          if (dx >= -4 && dx <= 4) {
            out_s[dx + 4][wr] = a[r] * invn1_s[wr] * i2;
          }
        }
      }
    }
    __syncthreads();
    #pragma unroll
    for (int kidx = 0; kidx < 3; ++kidx) {
      const int k = kidx * 256 + t;
      if (k < 9 * 64) {
        const int dx = k >> 6;
        const int wl = k & 63;
        const int d  = dyi * 9 + dx;
        out[(((size_t)b * 81 + d) * NH + h) * NW + w0 + wl] = out_s[dx][wl];
      }
    }
  }
}

extern "C" void kernel_launch(void* const* d_in, const int* in_sizes, int n_in,
                              void* d_out, int out_size, void* d_ws, size_t ws_size,
                              hipStream_t stream) {
  const float* f1 = (const float*)d_in[0];
  const float* f2 = (const float*)d_in[1];
  float* out = (float*)d_out;
  if (d_ws != nullptr && ws_size >= WS_NEEDED) {
    unsigned short* fn = (unsigned short*)d_ws;
    float* invn = (float*)((char*)d_ws + IVOFF);
    conv_hwc8<<<dim3(920, 2), 256, 0, stream>>>(f1, f2, fn, invn);
    corr_hwc2<<<dim3(920), 128, 0, stream>>>(fn, invn, out);
  } else {
    corr_mfma<<<dim3(5, NH, NB), 256, 0, stream>>>(f1, f2, out);
  }
}